// Round 1
// baseline (6262.236 us; speedup 1.0000x reference)
//
#include <hip/hip_runtime.h>
#include <cstddef>
#include <cstdint>

// ---------------- problem dims ----------------
#define T_ 32
#define A_ 32
#define F_ 4
#define E_ 256
#define FE_ 1024
#define H_ 768
#define H2_ 1536
#define G4_ 3072     // 4*H
#define G8_ 6144     // 4*H2
#define DTOK_ 256
#define DDEC_ 1280
#define SEQ_ 1024    // T*A

// ---------------- ws layout (float offsets) ----------------
constexpr size_t OFF_PACKED = 0;                       // 1024*1024
constexpr size_t OFF_XF     = OFF_PACKED + 1024*1024;  // 1024*3072
constexpr size_t OFF_XB     = OFF_XF + 1024*3072;
constexpr size_t OFF_XD     = OFF_XB + 1024*3072;      // 32*6144
constexpr size_t OFF_XDIN   = OFF_XD + 32*6144;        // 32*1280
constexpr size_t OFF_ENC    = OFF_XDIN + 32*1280;      // 1024*1536
constexpr size_t OFF_HN     = OFF_ENC + 1024*1536;     // 32*1536
constexpr size_t OFF_AMAT   = OFF_HN + 32*1536;        // 32*1536
constexpr size_t OFF_C0     = OFF_AMAT + 32*1536;      // 1536
constexpr size_t OFF_HD     = OFF_C0 + 1536;           // 2*1536 (hd[0] = h0, filled by encoder)
constexpr size_t OFF_STATE  = OFF_HD + 2*1536;         // memset-from-here region
constexpr size_t OFF_HBF    = OFF_STATE;               // 2*768 fwd h double buffer
constexpr size_t OFF_HBB    = OFF_HBF + 2*768;         // 2*768 bwd
constexpr size_t OFF_FLAGS  = OFF_HBB + 2*768;         // 256 ints: [0:64) fwd, [64:128) bwd, [128:256) dec
constexpr size_t STATE_BYTES = (2*768*2 + 256) * 4;    // 13312

// ---------------- embed + decoder-input gather ----------------
__global__ void embed_k(const int* __restrict__ lattice, const int* __restrict__ inputs,
                        const int* __restrict__ gold, const int* __restrict__ sos,
                        const float* __restrict__ emb, const float* __restrict__ tok_emb,
                        float* __restrict__ packed, float* __restrict__ xdec_in) {
    int b = blockIdx.x, tid = threadIdx.x;
    if (b < SEQ_) {
        #pragma unroll
        for (int f = 0; f < F_; ++f) {
            int vid = lattice[b * F_ + f];
            packed[(size_t)b * FE_ + f * E_ + tid] = emb[(size_t)vid * E_ + tid];
        }
    } else {
        int t = b - SEQ_;  // 0..31
        for (int j = tid; j < DDEC_; j += 256) {
            float v;
            if (j < FE_) {
                int f = j >> 8, e2 = j & 255;
                int vid = (t == 0) ? sos[f]
                                   : lattice[(((t - 1) * A_) + gold[t - 1]) * F_ + f];
                v = emb[(size_t)vid * E_ + e2];
            } else {
                v = tok_emb[(size_t)inputs[t] * DTOK_ + (j - FE_)];
            }
            xdec_in[(size_t)t * DDEC_ + j] = v;
        }
    }
}

// ---------------- fp32 tiled GEMM: C[M,N] = A[M,K] @ B[K,N] + bias ----------------
#define BM 128
#define BN 128
#define BK 8
__global__ __launch_bounds__(256) void gemm_bias_k(
    const float* __restrict__ A, const float* __restrict__ B,
    const float* __restrict__ bias, float* __restrict__ C,
    int M, int N, int K) {
    __shared__ float As[BK][BM + 4];
    __shared__ float Bs[BK][BN + 4];
    int tid = threadIdx.x;
    int n0 = blockIdx.x * BN, m0 = blockIdx.y * BM;
    int tx = tid & 15, ty = tid >> 4;
    int lam = tid >> 1, lak = (tid & 1) * 4;   // A loader: row lam, k lak..lak+3
    int lbk = tid >> 5, lbn = (tid & 31) * 4;  // B loader: k lbk, cols lbn..+3
    float acc[8][8] = {};
    for (int k0 = 0; k0 < K; k0 += BK) {
        float4 av = make_float4(0.f, 0.f, 0.f, 0.f);
        if (m0 + lam < M)
            av = *(const float4*)(A + (size_t)(m0 + lam) * K + k0 + lak);
        float4 bv = *(const float4*)(B + (size_t)(k0 + lbk) * N + n0 + lbn);
        __syncthreads();
        As[lak + 0][lam] = av.x; As[lak + 1][lam] = av.y;
        As[lak + 2][lam] = av.z; As[lak + 3][lam] = av.w;
        *(float4*)&Bs[lbk][lbn] = bv;
        __syncthreads();
        #pragma unroll
        for (int kk = 0; kk < BK; ++kk) {
            float a[8], b[8];
            *(float4*)&a[0] = *(const float4*)&As[kk][ty * 8];
            *(float4*)&a[4] = *(const float4*)&As[kk][ty * 8 + 4];
            *(float4*)&b[0] = *(const float4*)&Bs[kk][tx * 8];
            *(float4*)&b[4] = *(const float4*)&Bs[kk][tx * 8 + 4];
            #pragma unroll
            for (int i = 0; i < 8; ++i)
                #pragma unroll
                for (int j = 0; j < 8; ++j)
                    acc[i][j] += a[i] * b[j];
        }
    }
    #pragma unroll
    for (int i = 0; i < 8; ++i) {
        int m = m0 + ty * 8 + i;
        if (m >= M) break;
        #pragma unroll
        for (int j = 0; j < 8; ++j) {
            int n = n0 + tx * 8 + j;
            float bb = bias ? bias[n] : 0.f;
            C[(size_t)m * N + n] = acc[i][j] + bb;
        }
    }
}

__device__ __forceinline__ float sigf(float x) { return 1.f / (1.f + __expf(-x)); }

// ---------------- persistent encoder LSTM (fwd + bwd) ----------------
// 128 blocks: blocks [0,64) fwd, [64,128) bwd. 768 threads: out = tid>>4 (48 gate
// outputs = 4 gates x 12 dims), kl = tid&15 (K split 768/16=48). Weights
// register-resident (48 VGPR/thread). Cross-block h exchange via agent-scope
// atomics (LLC-direct), flags release/poll.
__global__ __launch_bounds__(768, 1) void lstm_enc_k(
    const float* __restrict__ Xf, const float* __restrict__ Xb,
    const float* __restrict__ Whf, const float* __restrict__ Whb,
    float* __restrict__ enc, float* __restrict__ hbuf, int* __restrict__ flags,
    float* __restrict__ hd0, float* __restrict__ c0) {
    const int dir = blockIdx.x >> 6;
    const int wb  = blockIdx.x & 63;
    const float* X  = dir ? Xb : Xf;
    const float* Wh = dir ? Whb : Whf;
    float* hb = hbuf + dir * 1536;     // [2][768]
    int* flg  = flags + dir * 64;
    const int tid = threadIdx.x;
    const int out = tid >> 4, kl = tid & 15;
    const int q = out / 12, jj = out - q * 12;
    const int col = q * H_ + wb * 12 + jj;

    float w[48];
    {
        const float* wp = Wh + (size_t)(kl * 48) * G4_ + col;
        #pragma unroll
        for (int i = 0; i < 48; ++i) w[i] = wp[(size_t)i * G4_];
    }

    __shared__ float h_s[H_];
    __shared__ float gbuf[48];
    float c = 0.f;

    for (int t = 0; t < SEQ_; ++t) {
        if (tid < 64) {
            while (__hip_atomic_load(&flg[tid], __ATOMIC_RELAXED, __HIP_MEMORY_SCOPE_AGENT) < t) {}
        }
        __syncthreads();
        h_s[tid] = __hip_atomic_load(&hb[(t & 1) * H_ + tid], __ATOMIC_RELAXED,
                                     __HIP_MEMORY_SCOPE_AGENT);
        const int row = dir ? (SEQ_ - 1 - t) : t;
        float xg = 0.f;
        if (kl == 0) xg = X[(size_t)row * G4_ + col];
        __syncthreads();

        float s = 0.f;
        const float* hp = h_s + kl * 48;
        #pragma unroll
        for (int i = 0; i < 48; ++i) s += w[i] * hp[i];
        s += __shfl_xor(s, 1); s += __shfl_xor(s, 2);
        s += __shfl_xor(s, 4); s += __shfl_xor(s, 8);
        if (kl == 0) gbuf[out] = s + xg;
        __syncthreads();

        if (tid < 12) {
            float iv = gbuf[tid], fv = gbuf[12 + tid], gv = gbuf[24 + tid], ov = gbuf[36 + tid];
            c = sigf(fv) * c + sigf(iv) * tanhf(gv);
            float h = sigf(ov) * tanhf(c);
            int jg = wb * 12 + tid;
            enc[(size_t)row * H2_ + dir * H_ + jg] = h;
            __hip_atomic_store(&hb[((t + 1) & 1) * H_ + jg], h, __ATOMIC_RELAXED,
                               __HIP_MEMORY_SCOPE_AGENT);
            if (t == SEQ_ - 1) { hd0[dir * H_ + jg] = h; c0[dir * H_ + jg] = c; }
        }
        __syncthreads();
        if (tid == 0)
            __hip_atomic_store(&flg[wb], t + 1, __ATOMIC_RELEASE, __HIP_MEMORY_SCOPE_AGENT);
    }
}

// ---------------- persistent decoder LSTM ----------------
// 128 blocks x 768 threads; block owns 12 of 1536 dims; K=1536 split 16 -> 96
// register weights/thread.
__global__ __launch_bounds__(768, 1) void lstm_dec_k(
    const float* __restrict__ Xd, const float* __restrict__ Wh,
    float* __restrict__ Hn, float* __restrict__ hd,
    const float* __restrict__ c0, int* __restrict__ flg) {
    const int wb = blockIdx.x;
    const int tid = threadIdx.x;
    const int out = tid >> 4, kl = tid & 15;
    const int q = out / 12, jj = out - q * 12;
    const int col = q * H2_ + wb * 12 + jj;

    float w[96];
    {
        const float* wp = Wh + (size_t)(kl * 96) * G8_ + col;
        #pragma unroll
        for (int i = 0; i < 96; ++i) w[i] = wp[(size_t)i * G8_];
    }

    __shared__ float h_s[H2_];
    __shared__ float gbuf[48];
    float c = (tid < 12) ? c0[wb * 12 + tid] : 0.f;

    for (int t = 0; t < T_; ++t) {
        if (tid < 128) {
            while (__hip_atomic_load(&flg[tid], __ATOMIC_RELAXED, __HIP_MEMORY_SCOPE_AGENT) < t) {}
        }
        __syncthreads();
        h_s[tid] = __hip_atomic_load(&hd[(t & 1) * H2_ + tid], __ATOMIC_RELAXED,
                                     __HIP_MEMORY_SCOPE_AGENT);
        h_s[H_ + tid] = __hip_atomic_load(&hd[(t & 1) * H2_ + H_ + tid], __ATOMIC_RELAXED,
                                          __HIP_MEMORY_SCOPE_AGENT);
        float xg = 0.f;
        if (kl == 0) xg = Xd[(size_t)t * G8_ + col];
        __syncthreads();

        float s = 0.f;
        const float* hp = h_s + kl * 96;
        #pragma unroll
        for (int i = 0; i < 96; ++i) s += w[i] * hp[i];
        s += __shfl_xor(s, 1); s += __shfl_xor(s, 2);
        s += __shfl_xor(s, 4); s += __shfl_xor(s, 8);
        if (kl == 0) gbuf[out] = s + xg;
        __syncthreads();

        if (tid < 12) {
            float iv = gbuf[tid], fv = gbuf[12 + tid], gv = gbuf[24 + tid], ov = gbuf[36 + tid];
            c = sigf(fv) * c + sigf(iv) * tanhf(gv);
            float h = sigf(ov) * tanhf(c);
            int jg = wb * 12 + tid;
            Hn[(size_t)t * H2_ + jg] = h;
            __hip_atomic_store(&hd[((t + 1) & 1) * H2_ + jg], h, __ATOMIC_RELAXED,
                               __HIP_MEMORY_SCOPE_AGENT);
        }
        __syncthreads();
        if (tid == 0)
            __hip_atomic_store(&flg[wb], t + 1, __ATOMIC_RELEASE, __HIP_MEMORY_SCOPE_AGENT);
    }
}

// ---------------- scores: out[t][a] = Amat[t] . enc[t*32+a] ----------------
__global__ void score_k(const float* __restrict__ Amat, const float* __restrict__ enc,
                        float* __restrict__ outp) {
    int t = blockIdx.x, tid = threadIdx.x;
    __shared__ float a_s[H2_];
    for (int i = tid; i < H2_; i += 256) a_s[i] = Amat[(size_t)t * H2_ + i];
    __syncthreads();
    int aa = tid >> 3, p = tid & 7;
    const float4* e = (const float4*)(enc + (size_t)(t * A_ + aa) * H2_ + p * 192);
    const float4* ap = (const float4*)(a_s + p * 192);
    float s = 0.f;
    #pragma unroll
    for (int i = 0; i < 48; ++i) {
        float4 av = ap[i], ev = e[i];
        s += av.x * ev.x + av.y * ev.y + av.z * ev.z + av.w * ev.w;
    }
    s += __shfl_xor(s, 1); s += __shfl_xor(s, 2); s += __shfl_xor(s, 4);
    if (p == 0) outp[t * A_ + aa] = s;
}

// ---------------- host launch ----------------
extern "C" void kernel_launch(void* const* d_in, const int* in_sizes, int n_in,
                              void* d_out, int out_size, void* d_ws, size_t ws_size,
                              hipStream_t stream) {
    const int*   lattice = (const int*)d_in[0];
    const int*   inputs  = (const int*)d_in[2];
    const int*   gold    = (const int*)d_in[4];
    const int*   sos     = (const int*)d_in[5];
    const float* emb     = (const float*)d_in[6];
    const float* tok     = (const float*)d_in[7];
    const float* Wxf = (const float*)d_in[8];
    const float* Whf = (const float*)d_in[9];
    const float* bf  = (const float*)d_in[10];
    const float* Wxb = (const float*)d_in[11];
    const float* Whb = (const float*)d_in[12];
    const float* bb  = (const float*)d_in[13];
    const float* dWx = (const float*)d_in[14];
    const float* dWh = (const float*)d_in[15];
    const float* db  = (const float*)d_in[16];
    const float* aW  = (const float*)d_in[17];
    float* ws  = (float*)d_ws;
    float* out = (float*)d_out;

    float* packed = ws + OFF_PACKED;
    float* Xf     = ws + OFF_XF;
    float* Xb     = ws + OFF_XB;
    float* Xd     = ws + OFF_XD;
    float* xdin   = ws + OFF_XDIN;
    float* enc    = ws + OFF_ENC;
    float* Hn     = ws + OFF_HN;
    float* Amat   = ws + OFF_AMAT;
    float* c0     = ws + OFF_C0;
    float* hd     = ws + OFF_HD;
    float* hbuf   = ws + OFF_HBF;
    int*   flags  = (int*)(ws + OFF_FLAGS);

    // reset recurrent state + flags (graph-replay safe)
    hipMemsetAsync((char*)d_ws + OFF_STATE * sizeof(float), 0, STATE_BYTES, stream);

    // embeddings + decoder input rows
    embed_k<<<SEQ_ + T_, 256, 0, stream>>>(lattice, inputs, gold, sos, emb, tok,
                                           packed, xdin);
    // X precomputes
    gemm_bias_k<<<dim3(G4_ / BN, SEQ_ / BM), 256, 0, stream>>>(packed, Wxf, bf, Xf,
                                                               SEQ_, G4_, FE_);
    gemm_bias_k<<<dim3(G4_ / BN, SEQ_ / BM), 256, 0, stream>>>(packed, Wxb, bb, Xb,
                                                               SEQ_, G4_, FE_);
    gemm_bias_k<<<dim3(G8_ / BN, 1), 256, 0, stream>>>(xdin, dWx, db, Xd,
                                                       T_, G8_, DDEC_);
    // recurrences
    lstm_enc_k<<<128, 768, 0, stream>>>(Xf, Xb, Whf, Whb, enc, hbuf, flags, hd, c0);
    lstm_dec_k<<<128, 768, 0, stream>>>(Xd, dWh, Hn, hd, c0, flags + 128);
    // attention epilogue
    gemm_bias_k<<<dim3(H2_ / BN, 1), 256, 0, stream>>>(Hn, aW, nullptr, Amat,
                                                       T_, H2_, H2_);
    score_k<<<T_, 256, 0, stream>>>(Amat, enc, out);
}

// Round 2
// 2894.030 us; speedup vs baseline: 2.1638x; 2.1638x over previous
//
#include <hip/hip_runtime.h>
#include <cstddef>
#include <cstdint>

// ---------------- problem dims ----------------
#define T_ 32
#define A_ 32
#define F_ 4
#define E_ 256
#define FE_ 1024
#define H_ 768
#define H2_ 1536
#define G4_ 3072     // 4*H
#define G8_ 6144     // 4*H2
#define DTOK_ 256
#define DDEC_ 1280
#define SEQ_ 1024    // T*A

// ---------------- ws layout (float offsets) ----------------
constexpr size_t OFF_PACKED  = 0;                          // 1024*1024
constexpr size_t OFF_XF      = OFF_PACKED + 1024ull*1024;  // 1024*3072
constexpr size_t OFF_XB      = OFF_XF + 1024ull*3072;
constexpr size_t OFF_XD      = OFF_XB + 1024ull*3072;      // 32*6144
constexpr size_t OFF_XDIN    = OFF_XD + 32*6144;           // 32*1280
constexpr size_t OFF_ENC     = OFF_XDIN + 32*1280;         // 1024*1536
constexpr size_t OFF_HN      = OFF_ENC + 1024ull*1536;     // 32*1536
constexpr size_t OFF_AMAT    = OFF_HN + 32*1536;           // 32*1536
constexpr size_t OFF_C0      = OFF_AMAT + 32*1536;         // 1536
constexpr size_t OFF_PAIRS_E = OFF_C0 + 1536;              // enc pairs: 2dir x 2par x 768 u64 = 6144 floats
constexpr size_t OFF_PAIRS_D = OFF_PAIRS_E + 6144;         // dec pairs: 2par x 1536 u64 = 6144 floats
constexpr size_t MEMSET_BYTES = (6144 + 6144) * 4;         // 49152

__device__ __forceinline__ float sigf(float x) { return 1.f / (1.f + __expf(-x)); }

// ---------------- embed + decoder-input gather ----------------
__global__ void embed_k(const int* __restrict__ lattice, const int* __restrict__ inputs,
                        const int* __restrict__ gold, const int* __restrict__ sos,
                        const float* __restrict__ emb, const float* __restrict__ tok_emb,
                        float* __restrict__ packed, float* __restrict__ xdec_in) {
    int b = blockIdx.x, tid = threadIdx.x;
    if (b < SEQ_) {
        #pragma unroll
        for (int f = 0; f < F_; ++f) {
            int vid = lattice[b * F_ + f];
            packed[(size_t)b * FE_ + f * E_ + tid] = emb[(size_t)vid * E_ + tid];
        }
    } else {
        int t = b - SEQ_;  // 0..31
        for (int j = tid; j < DDEC_; j += 256) {
            float v;
            if (j < FE_) {
                int f = j >> 8, e2 = j & 255;
                int vid = (t == 0) ? sos[f]
                                   : lattice[(((t - 1) * A_) + gold[t - 1]) * F_ + f];
                v = emb[(size_t)vid * E_ + e2];
            } else {
                v = tok_emb[(size_t)inputs[t] * DTOK_ + (j - FE_)];
            }
            xdec_in[(size_t)t * DDEC_ + j] = v;
        }
    }
}

// ---------------- fp32 tiled GEMM: C[M,N] = A[M,K] @ B[K,N] + bias ----------------
#define BM 128
#define BN 128
#define BK 8
__device__ __forceinline__ void gemm_body(
    const float* __restrict__ A, const float* __restrict__ B,
    const float* __restrict__ bias, float* __restrict__ C,
    int M, int N, int K, int n0, int m0) {
    __shared__ float As[BK][BM + 4];
    __shared__ float Bs[BK][BN + 4];
    int tid = threadIdx.x;
    int tx = tid & 15, ty = tid >> 4;
    int lam = tid >> 1, lak = (tid & 1) * 4;
    int lbk = tid >> 5, lbn = (tid & 31) * 4;
    float acc[8][8] = {};
    for (int k0 = 0; k0 < K; k0 += BK) {
        float4 av = make_float4(0.f, 0.f, 0.f, 0.f);
        if (m0 + lam < M)
            av = *(const float4*)(A + (size_t)(m0 + lam) * K + k0 + lak);
        float4 bv = *(const float4*)(B + (size_t)(k0 + lbk) * N + n0 + lbn);
        __syncthreads();
        As[lak + 0][lam] = av.x; As[lak + 1][lam] = av.y;
        As[lak + 2][lam] = av.z; As[lak + 3][lam] = av.w;
        *(float4*)&Bs[lbk][lbn] = bv;
        __syncthreads();
        #pragma unroll
        for (int kk = 0; kk < BK; ++kk) {
            float a[8], b[8];
            *(float4*)&a[0] = *(const float4*)&As[kk][ty * 8];
            *(float4*)&a[4] = *(const float4*)&As[kk][ty * 8 + 4];
            *(float4*)&b[0] = *(const float4*)&Bs[kk][tx * 8];
            *(float4*)&b[4] = *(const float4*)&Bs[kk][tx * 8 + 4];
            #pragma unroll
            for (int i = 0; i < 8; ++i)
                #pragma unroll
                for (int j = 0; j < 8; ++j)
                    acc[i][j] += a[i] * b[j];
        }
    }
    #pragma unroll
    for (int i = 0; i < 8; ++i) {
        int m = m0 + ty * 8 + i;
        if (m >= M) break;
        #pragma unroll
        for (int j = 0; j < 8; ++j) {
            int n = n0 + tx * 8 + j;
            float bb = bias ? bias[n] : 0.f;
            C[(size_t)m * N + n] = acc[i][j] + bb;
        }
    }
}

__global__ __launch_bounds__(256) void gemm_bias_k(
    const float* __restrict__ A, const float* __restrict__ B,
    const float* __restrict__ bias, float* __restrict__ C, int M, int N, int K) {
    gemm_body(A, B, bias, C, M, N, K, blockIdx.x * BN, blockIdx.y * BM);
}

// z-fused pair of GEMMs sharing A (fwd/bwd X precompute)
__global__ __launch_bounds__(256) void gemm_bias2_k(
    const float* __restrict__ A,
    const float* __restrict__ B0, const float* __restrict__ bias0, float* __restrict__ C0,
    const float* __restrict__ B1, const float* __restrict__ bias1, float* __restrict__ C1,
    int M, int N, int K) {
    const float* B = blockIdx.z ? B1 : B0;
    const float* bias = blockIdx.z ? bias1 : bias0;
    float* C = blockIdx.z ? C1 : C0;
    gemm_body(A, B, bias, C, M, N, K, blockIdx.x * BN, blockIdx.y * BM);
}

// ---------------- persistent encoder LSTM (fwd + bwd) ----------------
// 128 blocks: [0,64) fwd, [64,128) bwd; 768 threads. Thread (out=tid>>4, kl=tid&15):
// out = gate-output index (4 gates x 12 dims), kl = K-split of 16 (48 MACs/thread,
// register weights). h exchange: per-dim {tag,value} u64 pairs, double-buffered by
// step parity, one relaxed 8B agent atomic each way. Thread tid polls pair[tid] 1:1.
__global__ __launch_bounds__(768, 1) void lstm_enc_k(
    const float* __restrict__ Xf, const float* __restrict__ Xb,
    const float* __restrict__ Whf, const float* __restrict__ Whb,
    float* __restrict__ enc, unsigned long long* __restrict__ pairsE,
    unsigned long long* __restrict__ pairsD, float* __restrict__ c0) {
    const int dir = blockIdx.x >> 6;
    const int wb  = blockIdx.x & 63;
    const float* X  = dir ? Xb : Xf;
    const float* Wh = dir ? Whb : Whf;
    unsigned long long* pp = pairsE + (size_t)dir * (2 * 768);
    const int tid = threadIdx.x;
    const int out = tid >> 4, kl = tid & 15;
    const int q = out / 12, jj = out - q * 12;
    const int col = q * H_ + wb * 12 + jj;
    const int xcol = (tid / 12) * H_ + wb * 12 + (tid % 12);  // for tid<48

    float w[12][4];
    #pragma unroll
    for (int i = 0; i < 12; ++i) {
        int kb = kl * 4 + 64 * i;
        #pragma unroll
        for (int e = 0; e < 4; ++e)
            w[i][e] = Wh[(size_t)(kb + e) * G4_ + col];
    }

    __shared__ float h_s[768];
    __shared__ float gbuf[48];
    __shared__ float xs[48];
    float c = 0.f;

    for (int t = 0; t < SEQ_; ++t) {
        const int row = dir ? (SEQ_ - 1 - t) : t;
        float xv = 0.f;
        if (tid < 48) xv = X[(size_t)row * G4_ + xcol];   // prefetch, hidden under poll

        unsigned long long* p = pp + (size_t)(t & 1) * 768 + tid;
        unsigned long long v = __hip_atomic_load(p, __ATOMIC_RELAXED, __HIP_MEMORY_SCOPE_AGENT);
        while ((unsigned)(v >> 32) != (unsigned)t)
            v = __hip_atomic_load(p, __ATOMIC_RELAXED, __HIP_MEMORY_SCOPE_AGENT);
        h_s[tid] = __uint_as_float((unsigned)v);
        __syncthreads();                                  // A: h_s ready

        float s = 0.f;
        #pragma unroll
        for (int i = 0; i < 12; ++i) {
            const float4 hv = *(const float4*)&h_s[kl * 4 + 64 * i];
            s += w[i][0] * hv.x + w[i][1] * hv.y + w[i][2] * hv.z + w[i][3] * hv.w;
        }
        s += __shfl_xor(s, 1); s += __shfl_xor(s, 2);
        s += __shfl_xor(s, 4); s += __shfl_xor(s, 8);
        if (kl == 0) gbuf[out] = s;
        if (tid < 48) xs[tid] = xv;
        __syncthreads();                                  // B: gbuf/xs ready

        if (tid < 12) {
            float iv = gbuf[tid]      + xs[tid];
            float fv = gbuf[12 + tid] + xs[12 + tid];
            float gv = gbuf[24 + tid] + xs[24 + tid];
            float ov = gbuf[36 + tid] + xs[36 + tid];
            c = sigf(fv) * c + sigf(iv) * tanhf(gv);
            float h = sigf(ov) * tanhf(c);
            int jg = wb * 12 + tid;
            enc[(size_t)row * H2_ + dir * H_ + jg] = h;
            unsigned long long pk =
                ((unsigned long long)(unsigned)(t + 1) << 32) | (unsigned long long)__float_as_uint(h);
            __hip_atomic_store(pp + (size_t)((t + 1) & 1) * 768 + jg, pk,
                               __ATOMIC_RELAXED, __HIP_MEMORY_SCOPE_AGENT);
            if (t == SEQ_ - 1) {  // seed decoder: tag 0, par 0
                __hip_atomic_store(pairsD + (size_t)(dir * H_ + jg),
                                   (unsigned long long)__float_as_uint(h),
                                   __ATOMIC_RELAXED, __HIP_MEMORY_SCOPE_AGENT);
                c0[dir * H_ + jg] = c;
            }
        }
        // no third barrier: step-t reads of h_s/gbuf/xs all precede barrier B(t);
        // step-t+1 writes all follow barrier A(t+1)/B(t+1).
    }
}

// ---------------- persistent decoder LSTM ----------------
// 128 blocks x 768 threads; block owns 12 of 1536 dims (48 gate sums); K=1536,
// KL=16 -> 96 register weights/thread. Thread polls pairs tid and tid+768.
__global__ __launch_bounds__(768, 1) void lstm_dec_k(
    const float* __restrict__ Xd, const float* __restrict__ Wh,
    float* __restrict__ Hn, unsigned long long* __restrict__ pairs,
    const float* __restrict__ c0) {
    const int wb = blockIdx.x;
    const int tid = threadIdx.x;
    const int out = tid >> 4, kl = tid & 15;
    const int q = out / 12, jj = out - q * 12;
    const int col = q * H2_ + wb * 12 + jj;
    const int xcol = (tid / 12) * H2_ + wb * 12 + (tid % 12);

    float w[24][4];
    #pragma unroll
    for (int i = 0; i < 24; ++i) {
        int kb = kl * 4 + 64 * i;
        #pragma unroll
        for (int e = 0; e < 4; ++e)
            w[i][e] = Wh[(size_t)(kb + e) * G8_ + col];
    }

    __shared__ float h_s[1536];
    __shared__ float gbuf[48];
    __shared__ float xs[48];
    float c = (tid < 12) ? c0[wb * 12 + tid] : 0.f;

    for (int t = 0; t < T_; ++t) {
        float xv = 0.f;
        if (tid < 48) xv = Xd[(size_t)t * G8_ + xcol];

        unsigned long long* p0 = pairs + (size_t)(t & 1) * 1536 + tid;
        unsigned long long v0 = __hip_atomic_load(p0, __ATOMIC_RELAXED, __HIP_MEMORY_SCOPE_AGENT);
        while ((unsigned)(v0 >> 32) != (unsigned)t)
            v0 = __hip_atomic_load(p0, __ATOMIC_RELAXED, __HIP_MEMORY_SCOPE_AGENT);
        unsigned long long* p1 = p0 + 768;
        unsigned long long v1 = __hip_atomic_load(p1, __ATOMIC_RELAXED, __HIP_MEMORY_SCOPE_AGENT);
        while ((unsigned)(v1 >> 32) != (unsigned)t)
            v1 = __hip_atomic_load(p1, __ATOMIC_RELAXED, __HIP_MEMORY_SCOPE_AGENT);
        h_s[tid]       = __uint_as_float((unsigned)v0);
        h_s[tid + 768] = __uint_as_float((unsigned)v1);
        __syncthreads();

        float s = 0.f;
        #pragma unroll
        for (int i = 0; i < 24; ++i) {
            const float4 hv = *(const float4*)&h_s[kl * 4 + 64 * i];
            s += w[i][0] * hv.x + w[i][1] * hv.y + w[i][2] * hv.z + w[i][3] * hv.w;
        }
        s += __shfl_xor(s, 1); s += __shfl_xor(s, 2);
        s += __shfl_xor(s, 4); s += __shfl_xor(s, 8);
        if (kl == 0) gbuf[out] = s;
        if (tid < 48) xs[tid] = xv;
        __syncthreads();

        if (tid < 12) {
            float iv = gbuf[tid]      + xs[tid];
            float fv = gbuf[12 + tid] + xs[12 + tid];
            float gv = gbuf[24 + tid] + xs[24 + tid];
            float ov = gbuf[36 + tid] + xs[36 + tid];
            c = sigf(fv) * c + sigf(iv) * tanhf(gv);
            float h = sigf(ov) * tanhf(c);
            int jg = wb * 12 + tid;
            Hn[(size_t)t * H2_ + jg] = h;
            unsigned long long pk =
                ((unsigned long long)(unsigned)(t + 1) << 32) | (unsigned long long)__float_as_uint(h);
            __hip_atomic_store(pairs + (size_t)((t + 1) & 1) * 1536 + jg, pk,
                               __ATOMIC_RELAXED, __HIP_MEMORY_SCOPE_AGENT);
        }
    }
}

// ---------------- scores: out[t][a] = Amat[t] . enc[t*32+a] ----------------
__global__ void score_k(const float* __restrict__ Amat, const float* __restrict__ enc,
                        float* __restrict__ outp) {
    int t = blockIdx.x, tid = threadIdx.x;
    __shared__ float a_s[H2_];
    for (int i = tid; i < H2_; i += 256) a_s[i] = Amat[(size_t)t * H2_ + i];
    __syncthreads();
    int aa = tid >> 3, p = tid & 7;
    const float4* e = (const float4*)(enc + (size_t)(t * A_ + aa) * H2_ + p * 192);
    const float4* ap = (const float4*)(a_s + p * 192);
    float s = 0.f;
    #pragma unroll
    for (int i = 0; i < 48; ++i) {
        float4 av = ap[i], ev = e[i];
        s += av.x * ev.x + av.y * ev.y + av.z * ev.z + av.w * ev.w;
    }
    s += __shfl_xor(s, 1); s += __shfl_xor(s, 2); s += __shfl_xor(s, 4);
    if (p == 0) outp[t * A_ + aa] = s;
}

// ---------------- host launch ----------------
extern "C" void kernel_launch(void* const* d_in, const int* in_sizes, int n_in,
                              void* d_out, int out_size, void* d_ws, size_t ws_size,
                              hipStream_t stream) {
    const int*   lattice = (const int*)d_in[0];
    const int*   inputs  = (const int*)d_in[2];
    const int*   gold    = (const int*)d_in[4];
    const int*   sos     = (const int*)d_in[5];
    const float* emb     = (const float*)d_in[6];
    const float* tok     = (const float*)d_in[7];
    const float* Wxf = (const float*)d_in[8];
    const float* Whf = (const float*)d_in[9];
    const float* bf  = (const float*)d_in[10];
    const float* Wxb = (const float*)d_in[11];
    const float* Whb = (const float*)d_in[12];
    const float* bb  = (const float*)d_in[13];
    const float* dWx = (const float*)d_in[14];
    const float* dWh = (const float*)d_in[15];
    const float* db  = (const float*)d_in[16];
    const float* aW  = (const float*)d_in[17];
    float* ws  = (float*)d_ws;
    float* out = (float*)d_out;

    float* packed = ws + OFF_PACKED;
    float* Xf     = ws + OFF_XF;
    float* Xb     = ws + OFF_XB;
    float* Xd     = ws + OFF_XD;
    float* xdin   = ws + OFF_XDIN;
    float* enc    = ws + OFF_ENC;
    float* Hn     = ws + OFF_HN;
    float* Amat   = ws + OFF_AMAT;
    float* c0     = ws + OFF_C0;
    unsigned long long* pairsE = (unsigned long long*)(ws + OFF_PAIRS_E);
    unsigned long long* pairsD = (unsigned long long*)(ws + OFF_PAIRS_D);

    // reset pair tags (graph-replay safe; {tag=0,val=0} == initial h state)
    hipMemsetAsync((char*)d_ws + OFF_PAIRS_E * sizeof(float), 0, MEMSET_BYTES, stream);

    embed_k<<<SEQ_ + T_, 256, 0, stream>>>(lattice, inputs, gold, sos, emb, tok,
                                           packed, xdin);
    gemm_bias2_k<<<dim3(G4_ / BN, SEQ_ / BM, 2), 256, 0, stream>>>(
        packed, Wxf, bf, Xf, Wxb, bb, Xb, SEQ_, G4_, FE_);
    gemm_bias_k<<<dim3(G8_ / BN, 1), 256, 0, stream>>>(xdin, dWx, db, Xd,
                                                       T_, G8_, DDEC_);
    lstm_enc_k<<<128, 768, 0, stream>>>(Xf, Xb, Whf, Whb, enc, pairsE, pairsD, c0);
    lstm_dec_k<<<128, 768, 0, stream>>>(Xd, dWh, Hn, pairsD, c0);
    gemm_bias_k<<<dim3(H2_ / BN, 1), 256, 0, stream>>>(Hn, aW, nullptr, Amat,
                                                       T_, H2_, H2_);
    score_k<<<T_, 256, 0, stream>>>(Amat, enc, out);
}